// Round 5
// baseline (370.854 us; speedup 1.0000x reference)
//
#include <hip/hip_runtime.h>
#include <cmath>

#define B_ 32
#define N_ 4096
#define IN_DIM 125
#define ADIM 128
#define KDIM 64
#define DMODEL 1024
#define HID 64
#define KEFF 256
#define EPS_ 1e-6f
typedef unsigned long long ull;

// ---------- k0: convert MLP weights to f64 (once per launch) ----------
__global__ __launch_bounds__(256) void k0_cvt(
    const float* __restrict__ W1, const float* __restrict__ b1,
    const float* __restrict__ W2, const float* __restrict__ b2,
    double* __restrict__ W1D, double* __restrict__ b1D,
    double* __restrict__ W2D, double* __restrict__ b2D)
{
  int t = blockIdx.x * 256 + threadIdx.x;
  if (t < IN_DIM * HID) W1D[t] = (double)W1[t];
  if (t < HID) { b1D[t] = (double)b1[t]; W2D[t] = (double)W2[t]; }
  if (t == 0) b2D[0] = (double)b2[0];
}

// ---------- k1: saliency MLP fp64; depth-3 scalar W prefetch ----------
#define K1_PTS 64
__global__ __launch_bounds__(512) void k1_saliency(
    const float* __restrict__ x, const double* __restrict__ W1D,
    const double* __restrict__ b1D, const double* __restrict__ W2D,
    const double* __restrict__ b2D, double* __restrict__ salD,
    float* __restrict__ salF)
{
  __shared__ double smem[4000];              // 32000B: xs overlay + reduce
  float* xs = (float*)smem;                  // [64][125]
  int tid = threadIdx.x;
  int p0 = blockIdx.x * K1_PTS;

  { const float4* src = (const float4*)(x + (size_t)p0 * IN_DIM);
    float4* dst = (float4*)xs;
    for (int e = tid; e < (K1_PTS * IN_DIM) / 4; e += 512) dst[e] = src[e]; }
  __syncthreads();

  int wv = __builtin_amdgcn_readfirstlane(tid >> 6);
  int lane = tid & 63;
  int jb = wv * 8;

  double acc[8];
  #pragma unroll
  for (int jj = 0; jj < 8; ++jj) acc[jj] = b1D[jb + jj];

  const float* xr = xs + lane * IN_DIM;      // stride 125: 2-way LDS = free
  const double* Wb = W1D + jb;               // row d at Wb + d*64 (uniform)

  double A[8], Bb[8], C[8];
  #pragma unroll
  for (int q = 0; q < 8; ++q) { A[q] = Wb[q]; Bb[q] = Wb[64 + q]; C[q] = Wb[128 + q]; }

  #pragma unroll 1
  for (int g = 0; g < 41; ++g) {             // rows 0..122; 3-deep prefetch
    int d = g * 3;
    int r3 = (d + 3 < 125) ? d + 3 : 124;
    int r4 = (d + 4 < 125) ? d + 4 : 124;
    int r5 = (d + 5 < 125) ? d + 5 : 124;
    float xa = xr[d], xb = xr[d + 1], xc = xr[d + 2];
    double xda = (double)xa;
    #pragma unroll
    for (int jj = 0; jj < 8; ++jj) acc[jj] = fma(xda, A[jj], acc[jj]);
    #pragma unroll
    for (int q = 0; q < 8; ++q) A[q] = Wb[r3 * 64 + q];
    double xdb = (double)xb;
    #pragma unroll
    for (int jj = 0; jj < 8; ++jj) acc[jj] = fma(xdb, Bb[jj], acc[jj]);
    #pragma unroll
    for (int q = 0; q < 8; ++q) Bb[q] = Wb[r4 * 64 + q];
    double xdc = (double)xc;
    #pragma unroll
    for (int jj = 0; jj < 8; ++jj) acc[jj] = fma(xdc, C[jj], acc[jj]);
    #pragma unroll
    for (int q = 0; q < 8; ++q) C[q] = Wb[r5 * 64 + q];
  }
  { // tail: rows 123 (A), 124 (Bb)
    double xda = (double)xr[123];
    #pragma unroll
    for (int jj = 0; jj < 8; ++jj) acc[jj] = fma(xda, A[jj], acc[jj]);
    double xdb = (double)xr[124];
    #pragma unroll
    for (int jj = 0; jj < 8; ++jj) acc[jj] = fma(xdb, Bb[jj], acc[jj]);
  }

  double part = 0.0;
  #pragma unroll
  for (int jj = 0; jj < 8; ++jj)
    part = fma(fmax(acc[jj], 0.0), W2D[jb + jj], part);
  __syncthreads();
  double* red = smem;                        // [8][64] overlay
  red[wv * K1_PTS + lane] = part;
  __syncthreads();
  if (tid < K1_PTS) {
    double s = b2D[0];
    #pragma unroll
    for (int w = 0; w < 8; ++w) s += red[w * K1_PTS + tid];
    double sg = 1.0 / (1.0 + exp(-s));
    salD[p0 + tid] = sg;                     // f64 sort key (monotone == y*)
    salF[p0 + tid] = (float)sg;
  }
}

// ---- kB: sort 512-chunk desc on salD bits + chunk partial sums ----
// sal in (0,1): exp(2v) bounded -> softmax needs no max-subtract, so
// chunk-local Sexp / Ssal are enough for kC to finish softmax+cumsum.
__global__ __launch_bounds__(256) void kB_sortsum(
    const double* __restrict__ salD, ull* __restrict__ candK,
    int* __restrict__ candI, float* __restrict__ chunkSal,
    float* __restrict__ chunkExp)
{
  __shared__ ull K[512];
  __shared__ int I[512];
  __shared__ float rs[4], re[4];
  int bid = blockIdx.x, t = threadIdx.x;
  int b = bid >> 3, c = bid & 7;
  const double* y = salD + (size_t)b * N_ + c * 512;
  double v0 = y[t], v1 = y[t + 256];
  K[t] = __double_as_longlong(v0);       I[t] = c * 512 + t;
  K[t + 256] = __double_as_longlong(v1); I[t + 256] = c * 512 + t + 256;
  float sv = (float)v0 + (float)v1;
  float ev = expf(2.f * (float)v0) + expf(2.f * (float)v1);
  int lane = t & 63, wv = t >> 6;
  #pragma unroll
  for (int off = 32; off > 0; off >>= 1) {
    sv += __shfl_down(sv, off);
    ev += __shfl_down(ev, off);
  }
  if (lane == 0) { rs[wv] = sv; re[wv] = ev; }
  __syncthreads();                         // also publishes K/I
  if (t == 0) {
    chunkSal[bid] = (rs[0] + rs[1]) + (rs[2] + rs[3]);
    chunkExp[bid] = (re[0] + re[1]) + (re[2] + re[3]);
  }
  for (int k = 2; k <= 512; k <<= 1) {
    for (int j = k >> 1; j > 0; j >>= 1) {
      for (int i = t; i < 512; i += 256) {
        int l = i ^ j;
        if (l > i) {
          ull a = K[i], cc = K[l];
          int ai = I[i], ci = I[l];
          bool prec = (a > cc) || (a == cc && ai < ci);
          bool up = ((i & k) == 0);
          if (up ? !prec : prec) { K[i] = cc; K[l] = a; I[i] = ci; I[l] = ai; }
        }
      }
      __syncthreads();
    }
  }
  candK[(size_t)bid * 256 + t] = K[t];
  candI[(size_t)bid * 256 + t] = I[t];
}

// ---- kC: merge 8 sorted lists -> topidx; then softmax+cumsum writes ----
__global__ __launch_bounds__(256) void kC_merge_softmax(
    const ull* __restrict__ candK, const int* __restrict__ candI,
    const float* __restrict__ salF, const float* __restrict__ chunkSal,
    const float* __restrict__ chunkExp, int* __restrict__ topidx,
    float* __restrict__ ystar, float* __restrict__ csal)
{
  __shared__ ull K[2048];
  __shared__ int I[2048];
  __shared__ float coffs[8];
  __shared__ float sden;
  int b = blockIdx.x, t = threadIdx.x;

  if (t == 0) {
    float run = 0.f, den = 0.f;
    #pragma unroll
    for (int c2 = 0; c2 < 8; ++c2) {
      coffs[c2] = run;
      run += chunkSal[b * 8 + c2];
      den += chunkExp[b * 8 + c2];
    }
    sden = den;
  }
  for (int i = t; i < 2048; i += 256) {
    int r = i >> 9, o = i & 511;
    int lst = (o < 256) ? 2 * r : 2 * r + 1;
    int pos = (o < 256) ? o : 511 - o;
    K[i] = candK[(size_t)(b * 8 + lst) * 256 + pos];
    I[i] = candI[(size_t)(b * 8 + lst) * 256 + pos];
  }
  __syncthreads();

  #define CMPSWAP(i, l) { \
    ull a = K[i], cc = K[l]; \
    int ai = I[i], ci = I[l]; \
    bool prec = (a > cc) || (a == cc && ai < ci); \
    if (!prec) { K[i] = cc; K[l] = a; I[i] = ci; I[l] = ai; } }

  for (int j = 256; j > 0; j >>= 1) {
    for (int i = t; i < 2048; i += 256) {
      int l = i ^ j;
      if (l > i) CMPSWAP(i, l);
    }
    __syncthreads();
  }
  for (int i = t; i < 512; i += 256) {
    int pr = i >> 8, o = i & 255;
    int dst = pr * 1024 + 256 + o, src = pr * 1024 + 512 + 255 - o;
    K[dst] = K[src]; I[dst] = I[src];
  }
  __syncthreads();
  for (int j = 256; j > 0; j >>= 1) {
    for (int ii = t; ii < 1024; ii += 256) {
      int i = (ii < 512) ? ii : (ii + 512);
      int l = i ^ j;
      if (l > i) CMPSWAP(i, l);
    }
    __syncthreads();
  }
  for (int i = t; i < 256; i += 256) {
    K[256 + i] = K[1024 + 255 - i]; I[256 + i] = I[1024 + 255 - i];
  }
  __syncthreads();
  for (int j = 256; j > 0; j >>= 1) {
    for (int i = t; i < 512; i += 256) {
      int l = i ^ j;
      if (l > i) CMPSWAP(i, l);
    }
    __syncthreads();
  }
  topidx[b * KEFF + t] = I[t];
  #undef CMPSWAP

  // ---- phase B: ystar = exp(2v)/denom; csal = chunk-prefix cumsum / N ----
  float rden = 1.f / sden;
  int ch = t >> 5;                            // 16t/512
  int lane = t & 63;
  const float4* s4 = (const float4*)(salF + (size_t)b * N_ + 16 * t);
  float v[16];
  #pragma unroll
  for (int k = 0; k < 4; ++k) {
    float4 a = s4[k];
    v[4*k] = a.x; v[4*k+1] = a.y; v[4*k+2] = a.z; v[4*k+3] = a.w;
  }
  float e[16];
  #pragma unroll
  for (int i = 0; i < 16; ++i) e[i] = expf(2.f * v[i]);
  float p[16];
  p[0] = v[0];
  #pragma unroll
  for (int i = 1; i < 16; ++i) p[i] = p[i-1] + v[i];
  float T = p[15];
  // 64-lane inclusive scan of thread totals, then fix 32-lane segments
  float incl = T;
  #pragma unroll
  for (int off = 1; off < 64; off <<= 1) {
    float nv = __shfl_up(incl, off);
    if (lane >= off) incl += nv;
  }
  float incl31 = __shfl(incl, 31);
  float exclT = incl - T - ((lane >= 32) ? incl31 : 0.f);
  float base = coffs[ch] + exclT;

  float4* y4 = (float4*)(ystar + (size_t)b * N_ + 16 * t);
  float4* c4 = (float4*)(csal  + (size_t)b * N_ + 16 * t);
  const float invN = 1.f / (float)N_;
  #pragma unroll
  for (int k = 0; k < 4; ++k) {
    float4 yo, co;
    yo.x = e[4*k]   * rden; co.x = (base + p[4*k])   * invN;
    yo.y = e[4*k+1] * rden; co.y = (base + p[4*k+1]) * invN;
    yo.z = e[4*k+2] * rden; co.z = (base + p[4*k+2]) * invN;
    yo.w = e[4*k+3] * rden; co.w = (base + p[4*k+3]) * invN;
    y4[k] = yo;
    c4[k] = co;
  }
}

// ---- K4: fused gather -> normalize -> lift -> proj -> tokens ----
// 64 points/block, 2 col-halves -> 256 blocks. lane = point everywhere:
// per-lane LDS reads hit distinct banks (pad), wave-uniform W rows come
// from SGPRs (s_load), stores transpose through LDS for coalescing.
__global__ __launch_bounds__(256) void k4_fused(
    const float* __restrict__ x, const float* __restrict__ salF,
    const float* __restrict__ csal, const int* __restrict__ topidx,
    const float* __restrict__ lift_W, const float* __restrict__ lift_b,
    const float* __restrict__ mu, const float* __restrict__ sigma,
    const float* __restrict__ proj_W, const float* __restrict__ proj_b,
    float* __restrict__ tokens)
{
  __shared__ float su[8448];          // sd[64][129] ∪ st[4][64][33]
  __shared__ float sc[64][65];        // cloud, padded
  __shared__ float snf[64];
  __shared__ int sidx[64];
  #define SD(p, a) su[(p) * 129 + (a)]
  #define ST(w, p, j) su[((w) * 64 + (p)) * 33 + (j)]

  int t = threadIdx.x, bid = blockIdx.x;
  int b = bid >> 3, pgi = (bid >> 1) & 3, h = bid & 1;
  int p0 = pgi * 64;

  if (t < 64) sidx[t] = topidx[b * KEFF + p0 + t];
  __syncthreads();

  for (int e = t; e < 64 * ADIM; e += 256) {
    int p = e >> 7, a = e & 127;
    int n = sidx[p];
    int base = b * N_ + n;
    float v;
    if (a < IN_DIM)          v = x[(size_t)base * IN_DIM + a];
    else if (a == IN_DIM)    v = salF[base];
    else if (a == IN_DIM+1)  v = (float)n / (float)(N_ - 1);
    else                     v = csal[base];
    SD(p, a) = v;
  }
  __syncthreads();

  { int p = t >> 2, l4 = t & 3;
    float ss = 0.f;
    for (int a = l4; a < ADIM; a += 4) { float v = SD(p, a); ss = fmaf(v, v, ss); }
    ss += __shfl_down(ss, 2);
    ss += __shfl_down(ss, 1);
    if (l4 == 0) snf[p] = 1.f / (sqrtf(ss) + EPS_); }
  __syncthreads();

  for (int e = t; e < 64 * ADIM; e += 256) {
    int p = e >> 7, a = e & 127;
    SD(p, a) = (SD(p, a) * snf[p] - mu[a]) / sigma[a];
  }
  __syncthreads();

  int wv = __builtin_amdgcn_readfirstlane(t >> 6);
  int lane = t & 63;

  { // lift: wave wv owns k in [16wv, 16wv+16); lane = point
    float acc[16];
    const float* lb = lift_b + wv * 16;             // uniform -> s_load
    #pragma unroll
    for (int j = 0; j < 16; ++j) acc[j] = lb[j];
    #pragma unroll 1
    for (int a = 0; a < ADIM; ++a) {
      float xv = SD(lane, a);                       // distinct banks (pad 129)
      const float* wr = lift_W + a * KDIM + wv * 16; // uniform -> s_load
      #pragma unroll
      for (int j = 0; j < 16; ++j) acc[j] = fmaf(xv, wr[j], acc[j]);
    }
    #pragma unroll
    for (int j = 0; j < 16; ++j) sc[lane][wv * 16 + j] = acc[j];
  }
  __syncthreads();

  // proj: wave wv owns cols [h*512 + wv*128, +128), 4 passes of 32
  int colq = h * 512 + wv * 128;
  #pragma unroll 1
  for (int pp = 0; pp < 4; ++pp) {
    int colbase = colq + pp * 32;
    float acc[32];
    const float* pb = proj_b + colbase;             // uniform
    #pragma unroll
    for (int j = 0; j < 32; ++j) acc[j] = pb[j];
    #pragma unroll 1
    for (int c = 0; c < KDIM; ++c) {
      float xv = sc[lane][c];                       // distinct banks (pad 65)
      const float* wr = proj_W + (size_t)c * DMODEL + colbase;  // uniform
      #pragma unroll
      for (int j = 0; j < 32; ++j) acc[j] = fmaf(xv, wr[j], acc[j]);
    }
    #pragma unroll
    for (int j = 0; j < 32; ++j) ST(wv, lane, j) = acc[j];
    __syncthreads();
    { // cooperative coalesced store: 4 tiles x 64 rows x 32 cols
      #pragma unroll
      for (int ii = 0; ii < 8; ++ii) {
        int L = ii * 256 + t;                       // float4 index
        int w2 = L >> 9, r = (L >> 3) & 63, q = L & 7;
        float4 v4;
        v4.x = ST(w2, r, q * 4 + 0);
        v4.y = ST(w2, r, q * 4 + 1);
        v4.z = ST(w2, r, q * 4 + 2);
        v4.w = ST(w2, r, q * 4 + 3);
        int cb2 = h * 512 + w2 * 128 + pp * 32;
        *(float4*)(tokens + (size_t)(b * KEFF + p0 + r) * DMODEL + cb2 + q * 4) = v4;
      }
    }
    __syncthreads();
  }
  #undef SD
  #undef ST
}

extern "C" void kernel_launch(void* const* d_in, const int* in_sizes, int n_in,
                              void* d_out, int out_size, void* d_ws, size_t ws_size,
                              hipStream_t stream)
{
  const float* x      = (const float*)d_in[0];
  const float* W1     = (const float*)d_in[1];
  const float* b1     = (const float*)d_in[2];
  const float* W2     = (const float*)d_in[3];
  const float* b2     = (const float*)d_in[4];
  const float* lift_W = (const float*)d_in[5];
  const float* lift_b = (const float*)d_in[6];
  const float* mu     = (const float*)d_in[7];
  const float* sigma  = (const float*)d_in[8];
  const float* proj_W = (const float*)d_in[9];
  const float* proj_b = (const float*)d_in[10];

  float* tokens = (float*)d_out;                        // [B,256,1024]
  float* ystarF = tokens + (size_t)B_ * KEFF * DMODEL;  // [B,N]

  // workspace (~2.9 MB), 8B entities first
  char* wsb = (char*)d_ws;
  double* salD   = (double*)wsb;                            // 1 MB
  double* W1D    = salD + (size_t)B_ * N_;                  // 64 KB
  double* b1D    = W1D + IN_DIM * HID;
  double* W2D    = b1D + HID;
  double* b2D    = W2D + HID;                               // +pad
  ull*    candK  = (ull*)(b2D + 8);                         // 512 KB
  float*  salF   = (float*)(candK + (size_t)B_ * 2048);     // 512 KB
  float*  csalF  = salF + (size_t)B_ * N_;                  // 512 KB
  int*    candI  = (int*)(csalF + (size_t)B_ * N_);         // 256 KB
  int*    topidx = candI + (size_t)B_ * 2048;               // 32 KB
  float*  chunkSal = (float*)(topidx + B_ * KEFF);          // 1 KB
  float*  chunkExp = chunkSal + B_ * 8;                     // 1 KB

  k0_cvt<<<(IN_DIM * HID + 255) / 256, 256, 0, stream>>>(
      W1, b1, W2, b2, W1D, b1D, W2D, b2D);
  k1_saliency<<<(B_ * N_) / K1_PTS, 512, 0, stream>>>(
      x, W1D, b1D, W2D, b2D, salD, salF);
  kB_sortsum<<<B_ * 8, 256, 0, stream>>>(salD, candK, candI, chunkSal, chunkExp);
  kC_merge_softmax<<<B_, 256, 0, stream>>>(
      candK, candI, salF, chunkSal, chunkExp, topidx, ystarF, csalF);
  k4_fused<<<B_ * 8, 256, 0, stream>>>(
      x, salF, csalF, topidx, lift_W, lift_b, mu, sigma, proj_W, proj_b, tokens);
}

// Round 6
// 317.421 us; speedup vs baseline: 1.1683x; 1.1683x over previous
//
#include <hip/hip_runtime.h>
#include <hip/hip_cooperative_groups.h>
#include <cmath>

namespace cg = cooperative_groups;

#define B_ 32
#define N_ 4096
#define IN_DIM 125
#define ADIM 128
#define KDIM 64
#define DMODEL 1024
#define HID 64
#define KEFF 256
#define EPS_ 1e-6f
typedef unsigned long long ull;

// ---------- k1: saliency MLP in f64 (fp32 weights, in-register cvt) ----------
// 64 pts/block, 512 thr (8 waves). Wave w owns j-octet; lane owns 1 point ->
// 8 f64 acc. W rows prefetched depth-2 via uniform s_load (fp32, half bytes),
// cvt at FMA: f64(float(w)) is bitwise what k0 produced. 32KB LDS -> 4 blk/CU.
#define K1_PTS 64
__global__ __launch_bounds__(512) void k1_saliency(
    const float* __restrict__ x, const float* __restrict__ W1,
    const float* __restrict__ b1, const float* __restrict__ W2,
    const float* __restrict__ b2, double* __restrict__ salD,
    float* __restrict__ salF)
{
  __shared__ double smem[4000];              // 32000B: xs overlay + reduce
  float* xs = (float*)smem;                  // [64][125]
  int tid = threadIdx.x;
  int p0 = blockIdx.x * K1_PTS;

  { const float4* src = (const float4*)(x + (size_t)p0 * IN_DIM);
    float4* dst = (float4*)xs;
    for (int e = tid; e < (K1_PTS * IN_DIM) / 4; e += 512) dst[e] = src[e]; }
  __syncthreads();

  int wv = __builtin_amdgcn_readfirstlane(tid >> 6);
  int lane = tid & 63;
  int jb = wv * 8;

  double acc[8];
  #pragma unroll
  for (int jj = 0; jj < 8; ++jj) acc[jj] = (double)b1[jb + jj];

  const float* xr = xs + lane * IN_DIM;      // stride 125: 2-way LDS = free
  const float* Wb = W1 + jb;                 // row d at Wb + d*64 (uniform)
  float wA[8], wB[8];
  #pragma unroll
  for (int q = 0; q < 8; ++q) wA[q] = Wb[q];
  float xv0 = xr[0];

  #pragma unroll 1
  for (int d = 0; d < 124; d += 2) {
    float xv1 = xr[d + 1];
    #pragma unroll
    for (int q = 0; q < 8; ++q) wB[q] = Wb[(d + 1) * HID + q];
    double xd0 = (double)xv0;
    #pragma unroll
    for (int jj = 0; jj < 8; ++jj) acc[jj] = fma(xd0, (double)wA[jj], acc[jj]);
    xv0 = xr[d + 2];
    #pragma unroll
    for (int q = 0; q < 8; ++q) wA[q] = Wb[(d + 2) * HID + q];
    double xd1 = (double)xv1;
    #pragma unroll
    for (int jj = 0; jj < 8; ++jj) acc[jj] = fma(xd1, (double)wB[jj], acc[jj]);
  }
  { double xdl = (double)xv0;                // row 124 in wA
    #pragma unroll
    for (int jj = 0; jj < 8; ++jj) acc[jj] = fma(xdl, (double)wA[jj], acc[jj]); }

  double part = 0.0;
  #pragma unroll
  for (int jj = 0; jj < 8; ++jj)
    part = fma(fmax(acc[jj], 0.0), (double)W2[jb + jj], part);
  __syncthreads();
  double* red = smem;                        // [8][64] overlay
  red[wv * K1_PTS + lane] = part;
  __syncthreads();
  if (tid < K1_PTS) {
    double s = (double)b2[0];
    #pragma unroll
    for (int w = 0; w < 8; ++w) s += red[w * K1_PTS + tid];
    double sg = 1.0 / (1.0 + exp(-s));
    salD[p0 + tid] = sg;                     // f64 sort key (monotone == y*)
    salF[p0 + tid] = (float)sg;
  }
}

// ---------- k_coop: sort + merge + softmax/cumsum + gather/lift/proj ----------
// 256 blocks x 512 threads, cooperative (1 block/CU co-resident), dyn LDS 58240B.
#define SMEM_BYTES 58240

__global__ __launch_bounds__(512) void k_coop(
    const double* __restrict__ salD, const float* __restrict__ salF,
    ull* __restrict__ candK, int* __restrict__ candI,
    float* __restrict__ chunkSal, float* __restrict__ chunkExp,
    int* __restrict__ topidx, float* __restrict__ ystar,
    float* __restrict__ csal, const float* __restrict__ x,
    const float* __restrict__ lift_W, const float* __restrict__ lift_b,
    const float* __restrict__ mu, const float* __restrict__ sigma,
    const float* __restrict__ proj_W, const float* __restrict__ proj_b,
    float* __restrict__ tokens)
{
  extern __shared__ char sm[];
  cg::grid_group grid = cg::this_grid();
  int t = threadIdx.x, blk = blockIdx.x;
  int lane = t & 63, wv = t >> 6;

  // ================= Phase A: 512-chunk sort + chunk partial sums =========
  {
    ull* K  = (ull*)sm;                  // 512 keys (4KB)
    int* I  = (int*)(sm + 4096);         // 512 idx  (2KB)
    float* wsv = (float*)(sm + 6144);    // 8
    float* wev = (float*)(sm + 6208);    // 8
    int b = blk >> 3, c = blk & 7;
    const double* y = salD + (size_t)b * N_ + c * 512;
    double v = y[t];
    K[t] = __double_as_longlong(v);      // y in (0,1): bits monotone
    I[t] = c * 512 + t;
    float sv = (float)v;
    float ev = expf(2.f * sv);
    #pragma unroll
    for (int off = 32; off > 0; off >>= 1) {
      sv += __shfl_down(sv, off);
      ev += __shfl_down(ev, off);
    }
    if (lane == 0) { wsv[wv] = sv; wev[wv] = ev; }
    __syncthreads();                     // publishes K/I + wsv/wev
    if (t == 0) {
      float s8 = 0.f, e8 = 0.f;
      #pragma unroll
      for (int w = 0; w < 8; ++w) { s8 += wsv[w]; e8 += wev[w]; }
      chunkSal[blk] = s8; chunkExp[blk] = e8;
    }
    for (int k = 2; k <= 512; k <<= 1) {
      for (int j = k >> 1; j > 0; j >>= 1) {
        int l = t ^ j;
        if (l > t) {
          ull a = K[t], cc = K[l];
          int ai = I[t], ci = I[l];
          bool prec = (a > cc) || (a == cc && ai < ci);  // desc, tie->low idx
          bool up = ((t & k) == 0);
          if (up ? !prec : prec) { K[t] = cc; K[l] = a; I[t] = ci; I[l] = ai; }
        }
        __syncthreads();
      }
    }
    if (t < 256) {
      candK[(size_t)blk * 256 + t] = K[t];
      candI[(size_t)blk * 256 + t] = I[t];
    }
  }
  grid.sync();

  // ============ Phase B: blocks 0-31 merge || blocks 32-255 softmax =======
  {
    if (blk < 32) {
      ull* K = (ull*)sm;                 // 2048 (16KB)
      int* I = (int*)(sm + 16384);       // 2048 (8KB)
      int b = blk;
      for (int i = t; i < 2048; i += 512) {
        int r = i >> 9, o = i & 511;
        int lst = (o < 256) ? 2 * r : 2 * r + 1;
        int pos = (o < 256) ? o : 511 - o;
        K[i] = candK[(size_t)(b * 8 + lst) * 256 + pos];
        I[i] = candI[(size_t)(b * 8 + lst) * 256 + pos];
      }
      __syncthreads();
      #define CMPSWAP(i, l) { \
        ull a = K[i], cc = K[l]; \
        int ai = I[i], ci = I[l]; \
        bool prec = (a > cc) || (a == cc && ai < ci); \
        if (!prec) { K[i] = cc; K[l] = a; I[i] = ci; I[l] = ai; } }
      for (int j = 256; j > 0; j >>= 1) {
        for (int i = t; i < 2048; i += 512) {
          int l = i ^ j;
          if (l > i) CMPSWAP(i, l);
        }
        __syncthreads();
      }
      { int pr = t >> 8, o = t & 255;    // all 512 threads, disjoint src/dst
        int dst = pr * 1024 + 256 + o, src = pr * 1024 + 512 + 255 - o;
        K[dst] = K[src]; I[dst] = I[src]; }
      __syncthreads();
      for (int j = 256; j > 0; j >>= 1) {
        for (int ii = t; ii < 1024; ii += 512) {
          int i = (ii < 512) ? ii : (ii + 512);
          int l = i ^ j;
          if (l > i) CMPSWAP(i, l);
        }
        __syncthreads();
      }
      if (t < 256) { K[256 + t] = K[1024 + 255 - t]; I[256 + t] = I[1024 + 255 - t]; }
      __syncthreads();
      for (int j = 256; j > 0; j >>= 1) {
        if ((t ^ j) > t) CMPSWAP(t, t ^ j);
        __syncthreads();
      }
      if (t < 256) topidx[b * KEFF + t] = I[t];
      #undef CMPSWAP
    }
    // softmax/cumsum unit (all blocks; merge blocks take the last 32 units)
    __syncthreads();
    int u = (blk < 32) ? (224 + blk) : (blk - 32);
    int ub = u >> 3, uc = u & 7;
    float pre = 0.f, den = 0.f;
    #pragma unroll
    for (int i2 = 0; i2 < 8; ++i2) {
      float s = chunkSal[ub * 8 + i2];
      float e2 = chunkExp[ub * 8 + i2];
      if (i2 < uc) pre += s;
      den += e2;
    }
    float rden = 1.f / den;
    int gi = ub * N_ + uc * 512 + t;
    float v = salF[gi];
    float e = expf(2.f * v);
    float incl = v;
    #pragma unroll
    for (int off = 1; off < 64; off <<= 1) {
      float nv = __shfl_up(incl, off);
      if (lane >= off) incl += nv;
    }
    float* wtot = (float*)(sm + 32768);
    if (lane == 63) wtot[wv] = incl;
    __syncthreads();
    float woff = pre;
    #pragma unroll
    for (int w = 0; w < 8; ++w) if (w < wv) woff += wtot[w];
    ystar[gi] = e * rden;
    csal[gi] = (woff + incl) * (1.f / 4096.f);
  }
  grid.sync();

  // ====== Phase C: gather 32 pts -> normalize -> lift -> proj -> tokens ====
  {
    float* sd  = (float*)sm;             // [32][129] = 16512B
    float* sW  = (float*)(sm + 16512);   // [128][64] = 32768B
    float* sc  = (float*)(sm + 49280);   // [32][68]  = 8704B (16B-aligned f4)
    float* snf = (float*)(sm + 57984);   // 32
    int* sidx  = (int*)(sm + 58112);     // 32
    int b = blk >> 3, p0 = (blk & 7) * 32;

    if (t < 32) sidx[t] = topidx[b * KEFF + p0 + t];
    { const float4* src = (const float4*)lift_W;
      float4* dst = (float4*)sW;
      for (int e2 = t; e2 < 2048; e2 += 512) dst[e2] = src[e2]; }
    __syncthreads();

    for (int e2 = t; e2 < 32 * ADIM; e2 += 512) {
      int p = e2 >> 7, a = e2 & 127;
      int n = sidx[p];
      int gbase = b * N_ + n;
      float v;
      if (a < IN_DIM)          v = x[(size_t)gbase * IN_DIM + a];
      else if (a == IN_DIM)    v = salF[gbase];
      else if (a == IN_DIM+1)  v = (float)n / (float)(N_ - 1);
      else                     v = csal[gbase];
      sd[p * 129 + a] = v;
    }
    __syncthreads();

    { int p = t >> 4, l16 = t & 15;      // 32 pts x 16 lanes
      float ss = 0.f;
      for (int a = l16; a < ADIM; a += 16) { float vv = sd[p*129+a]; ss = fmaf(vv, vv, ss); }
      ss += __shfl_down(ss, 8);
      ss += __shfl_down(ss, 4);
      ss += __shfl_down(ss, 2);
      ss += __shfl_down(ss, 1);
      if (l16 == 0) snf[p] = 1.f / (sqrtf(ss) + EPS_); }
    __syncthreads();

    for (int e2 = t; e2 < 32 * ADIM; e2 += 512) {
      int p = e2 >> 7, a = e2 & 127;
      sd[p*129+a] = (sd[p*129+a] * snf[p] - mu[a]) / sigma[a];
    }
    __syncthreads();

    int wvu = __builtin_amdgcn_readfirstlane(wv);
    { // lift: wave wvu owns points [4*wvu, +4); lane = k-dim
      int pb4 = wvu * 4;
      float a0 = lift_b[lane], a1 = a0, a2 = a0, a3 = a0;
      #pragma unroll 1
      for (int a = 0; a < ADIM; ++a) {
        float wl = sW[a * KDIM + lane];          // stride-1: conflict-free
        a0 = fmaf(sd[(pb4+0)*129 + a], wl, a0);  // broadcasts
        a1 = fmaf(sd[(pb4+1)*129 + a], wl, a1);
        a2 = fmaf(sd[(pb4+2)*129 + a], wl, a2);
        a3 = fmaf(sd[(pb4+3)*129 + a], wl, a3);
      }
      sc[(pb4+0)*68 + lane] = a0;
      sc[(pb4+1)*68 + lane] = a1;
      sc[(pb4+2)*68 + lane] = a2;
      sc[(pb4+3)*68 + lane] = a3;
    }
    __syncthreads();

    // proj: 2 passes x 512 cols; thread owns 1 col x 32 points
    #pragma unroll 1
    for (int pp = 0; pp < 2; ++pp) {
      int col = pp * 512 + t;
      float acc[32];
      #pragma unroll
      for (int p = 0; p < 32; ++p) acc[p] = 0.f;
      float4 wcur;
      wcur.x = proj_W[0*DMODEL + col]; wcur.y = proj_W[1*DMODEL + col];
      wcur.z = proj_W[2*DMODEL + col]; wcur.w = proj_W[3*DMODEL + col];
      #pragma unroll 1
      for (int c = 0; c < KDIM; c += 4) {
        float4 wnext; wnext.x = wnext.y = wnext.z = wnext.w = 0.f;
        if (c + 4 < KDIM) {
          wnext.x = proj_W[(size_t)(c+4)*DMODEL + col];
          wnext.y = proj_W[(size_t)(c+5)*DMODEL + col];
          wnext.z = proj_W[(size_t)(c+6)*DMODEL + col];
          wnext.w = proj_W[(size_t)(c+7)*DMODEL + col];
        }
        #pragma unroll
        for (int p = 0; p < 32; ++p) {
          float4 cv = *(const float4*)&sc[p * 68 + c];   // 16B-aligned broadcast
          acc[p] = fmaf(cv.x, wcur.x, acc[p]);
          acc[p] = fmaf(cv.y, wcur.y, acc[p]);
          acc[p] = fmaf(cv.z, wcur.z, acc[p]);
          acc[p] = fmaf(cv.w, wcur.w, acc[p]);
        }
        wcur = wnext;
      }
      float pb = proj_b[col];
      #pragma unroll
      for (int p = 0; p < 32; ++p)
        tokens[(size_t)(b * KEFF + p0 + p) * DMODEL + col] = acc[p] + pb;
    }
  }
}

extern "C" void kernel_launch(void* const* d_in, const int* in_sizes, int n_in,
                              void* d_out, int out_size, void* d_ws, size_t ws_size,
                              hipStream_t stream)
{
  const float* x      = (const float*)d_in[0];
  const float* W1     = (const float*)d_in[1];
  const float* b1     = (const float*)d_in[2];
  const float* W2     = (const float*)d_in[3];
  const float* b2     = (const float*)d_in[4];
  const float* lift_W = (const float*)d_in[5];
  const float* lift_b = (const float*)d_in[6];
  const float* mu     = (const float*)d_in[7];
  const float* sigma  = (const float*)d_in[8];
  const float* proj_W = (const float*)d_in[9];
  const float* proj_b = (const float*)d_in[10];

  float* tokens = (float*)d_out;                        // [B,256,1024]
  float* ystarF = tokens + (size_t)B_ * KEFF * DMODEL;  // [B,N]

  // workspace (~2.8 MB)
  char* wsb = (char*)d_ws;
  double* salD     = (double*)wsb;                   // 1,048,576
  ull*    candK    = (ull*)(wsb + 1048576);          //   524,288
  float*  salF     = (float*)(wsb + 1572864);        //   524,288
  float*  csalF    = (float*)(wsb + 2097152);        //   524,288
  int*    candI    = (int*)(wsb + 2621440);          //   262,144
  int*    topidx   = (int*)(wsb + 2883584);          //    32,768
  float*  chunkSal = (float*)(wsb + 2916352);        //     1,024
  float*  chunkExp = (float*)(wsb + 2917376);        //     1,024

  k1_saliency<<<(B_ * N_) / K1_PTS, 512, 0, stream>>>(
      x, W1, b1, W2, b2, salD, salF);

  void* args[] = {
    (void*)&salD, (void*)&salF, (void*)&candK, (void*)&candI,
    (void*)&chunkSal, (void*)&chunkExp, (void*)&topidx, (void*)&ystarF,
    (void*)&csalF, (void*)&x, (void*)&lift_W, (void*)&lift_b,
    (void*)&mu, (void*)&sigma, (void*)&proj_W, (void*)&proj_b, (void*)&tokens };
  hipLaunchCooperativeKernel((const void*)k_coop, dim3(256), dim3(512),
                             args, SMEM_BYTES, stream);
}